// Round 12
// baseline (397.961 us; speedup 1.0000x reference)
//
#include <hip/hip_runtime.h>
#include <stdint.h>

typedef __attribute__((ext_vector_type(8))) short short8;
typedef __attribute__((ext_vector_type(4))) float f32x4;
typedef unsigned short ushort_t;

#define T_STEPS 10
#define BT 128
#define WPACK_BYTES (2048*1024)                 // 2048 chunks x 1 KiB
#define VBUF_OFF  WPACK_BYTES
#define HBF_OFF   (WPACK_BYTES + 8192)
#define H_ELEMS   (8192ull*T_STEPS*512)
#define HBF_BYTES (H_ELEMS*2)

typedef const __attribute__((address_space(1))) void gas_void;
typedef __attribute__((address_space(3))) void las_void;

__device__ __forceinline__ void gld_lds16(const void* g, void* l){
  __builtin_amdgcn_global_load_lds((gas_void*)g, (las_void*)l, 16, 0, 0);
}

__device__ __forceinline__ unsigned int pk2(float x, float y){
  unsigned int bx = __float_as_uint(x), by = __float_as_uint(y);
  bx = (bx + 0x7FFFu + ((bx>>16)&1u)) >> 16;     // RNE fp32->bf16
  by = (by + 0x7FFFu + ((by>>16)&1u)) >> 16;
  return bx | (by<<16);
}
__device__ __forceinline__ float sigf(float x){ return 1.f/(1.f + __expf(-x)); }
__device__ __forceinline__ float tanh_(float x){
  x = fminf(fmaxf(x, -15.f), 15.f);
  float e = __expf(2.f*x);
  return (e - 1.f)/(e + 1.f);
}

// ---- K0a: pack W_hh [2048][512] fp32 -> bf16 B-fragment chunks -------------
// chunk = ((jb*4 + jt)*4 + g)*16 + kc  (jb 0..7 j-block of 64, jt 0..3)
// in-chunk lane = khi*16 + jl ; j = jb*64 + jt*16 + jl ; k = kc*32 + khi*8 ..
__global__ __launch_bounds__(256) void k_pack(const float* __restrict__ Whh,
                                              ushort_t* __restrict__ wp){
  int id  = blockIdx.x*256 + threadIdx.x;
  int row = id >> 6;
  int ko  = (id & 63) * 8;
  const float* p = Whh + row*512 + ko;
  float4 a = *(const float4*)p, b = *(const float4*)(p+4);
  uint4 v;
  v.x = pk2(a.x,a.y); v.y = pk2(a.z,a.w);
  v.z = pk2(b.x,b.y); v.w = pk2(b.z,b.w);
  int g = row >> 9, j = row & 511;
  int jb = j >> 6, jt = (j >> 4) & 3, jl = j & 15;
  int kc = ko >> 5, khi = (ko >> 3) & 3, lane = khi*16 + jl;
  int chunk = ((jb*4 + jt)*4 + g)*16 + kc;
  *(uint4*)(wp + chunk*512 + lane*8) = v;
}

// ---- K0b -------------------------------------------------------------------
__global__ __launch_bounds__(256) void k_v(const float* __restrict__ fc1w,
                                           const float* __restrict__ fc1b,
                                           const float* __restrict__ fc2w,
                                           const float* __restrict__ fc2b,
                                           float* __restrict__ vout,
                                           float* __restrict__ bias0){
  __shared__ float red[4][64];
  int tid = threadIdx.x;
  if (blockIdx.x < 16){
    int j  = blockIdx.x*64 + (tid & 63);
    int hc = tid >> 6;
    float s = 0.f;
    for (int hh = hc*128; hh < hc*128 + 128; ++hh)
      s += fc2w[hh] * fc1w[hh*1024 + j];
    red[hc][tid & 63] = s;
    __syncthreads();
    if (tid < 64)
      vout[blockIdx.x*64 + tid] = red[0][tid]+red[1][tid]+red[2][tid]+red[3][tid];
  } else {
    if (tid < 64){
      float s = 0.f;
      for (int i = 0; i < 8; ++i){ int hh = i*64 + tid; s += fc2w[hh]*fc1b[hh]; }
      for (int m = 32; m; m >>= 1) s += __shfl_xor(s, m);
      if (tid == 0) *bias0 = s + fc2b[0];
    }
  }
}

// ---- K2 --------------------------------------------------------------------
__global__ __launch_bounds__(512) void k_init(const float* __restrict__ h,
                                              const float* __restrict__ v,
                                              const float* __restrict__ bias0,
                                              float* __restrict__ out){
  int w = threadIdx.x >> 6, lane = threadIdx.x & 63;
  float b0v = *bias0;
  const float* v2 = v + 512;
  for (int r = 0; r < 8; ++r){
    int b = blockIdx.x*64 + w*8 + r;
    const float* hp = h + ((size_t)b*T_STEPS + 9)*512 + lane*8;
    float4 x0 = *(const float4*)hp, x1 = *(const float4*)(hp+4);
    const float* vp = v2 + lane*8;
    float4 w0 = *(const float4*)vp, w1 = *(const float4*)(vp+4);
    float s = x0.x*w0.x + x0.y*w0.y + x0.z*w0.z + x0.w*w0.w
            + x1.x*w1.x + x1.y*w1.y + x1.z*w1.z + x1.w*w1.w;
    for (int m = 32; m; m >>= 1) s += __shfl_xor(s, m);
    if (lane == 0) out[b] = s + b0v;
  }
}

// ---- K0c: h fp32 -> bf16 in quad-major per-slice layout --------------------
// hbf granule(16B) index = ((tile*10 + t)*16 + kc)*512 + kq*128 + row
// (tile = b>>7, row = b&127, k = kc*32 + kq*8 + e). LDS-transposed: both the
// global read (row-major) and global write (slice-contig) are coalesced.
// grid = 64*10 = 640 blocks x 256 threads.
__global__ __launch_bounds__(256) void k_prep(const float* __restrict__ h,
                                              ushort_t* __restrict__ hbf){
  __shared__ __align__(16) ushort_t buf[16*512*8];   // 128 KiB
  int T = blockIdx.x / T_STEPS, t = blockIdx.x % T_STEPS;
  int tid = threadIdx.x;
  int row = tid >> 1, half = tid & 1;
  const float* src = h + ((size_t)(T*128 + row)*T_STEPS + t)*512 + half*256;
#pragma unroll
  for (int g = 0; g < 32; ++g){
    int k0 = half*256 + g*8;
    float4 a = *(const float4*)(src + g*8);
    float4 b = *(const float4*)(src + g*8 + 4);
    uint4 pk;
    pk.x = pk2(a.x,a.y); pk.y = pk2(a.z,a.w);
    pk.z = pk2(b.x,b.y); pk.w = pk2(b.z,b.w);
    int kc = k0 >> 5, kq = (k0 >> 3) & 3;
    *(uint4*)&buf[(size_t)(kc*512 + kq*128 + row)*8] = pk;
  }
  __syncthreads();
  ushort_t* dst = hbf + ((size_t)(T*T_STEPS + t)*16)*4096;
#pragma unroll
  for (int i = 0; i < 32; ++i){
    int gr = tid + i*256;
    *(uint4*)(dst + gr*8) = *(const uint4*)&buf[gr*8];
  }
}

// ============================================================================
// K1: BT=128 x j=64 per block, 512 blocks (2/CU, 4 waves/EU FORCED -> 128 VGPR).
// Per slice s (0..175): t = s<160 ? s>>4 : 9 ; kc = s&15.
// A slice (8KB) + W slice (12KB main / 4KB o) double-buffered via gld_lds;
// one barrier per slice; stage(s+1) issued before compute(s).
// All staging addresses hoisted to running/base pointers (R11 lesson: VALU).
// ============================================================================
template<bool PREP>
__global__ __launch_bounds__(512)
__attribute__((amdgpu_waves_per_eu(4, 4)))
void k_main(
    const float* __restrict__ h, const ushort_t* __restrict__ hbf,
    const float* __restrict__ y,
    const float* __restrict__ Wih, const float* __restrict__ bih,
    const float* __restrict__ bhh,
    const ushort_t* __restrict__ wpack, const float* __restrict__ v1,
    float* __restrict__ out)
{
  __shared__ __align__(16) ushort_t Ab[2][4096];   // 2 x 8 KiB
  __shared__ __align__(16) ushort_t Wb[2][6144];   // 2 x 12 KiB
  __shared__ float ys[BT*T_STEPS];                 // 5 KiB

  int tid = threadIdx.x;
  int w = tid >> 6, lane = tid & 63, lhi = lane >> 4, llo = lane & 15;
  int mh = w & 1, wj = w >> 1;                     // 2 mh x 4 wj
  int bid = blockIdx.x;
  int xcd = bid & 7, q = bid >> 3;
  int jb = q >> 3, tile = xcd*8 + (q & 7);         // tile's 8 jb-blocks: same XCD
  int b0 = tile * BT;

  float bias2[4], wihv[4];
#pragma unroll
  for (int g = 0; g < 4; ++g){
    int col = g*512 + jb*64 + wj*16 + llo;
    bias2[g] = bih[col] + bhh[col];
    wihv[g]  = Wih[col];
  }
  float v1v = v1[jb*64 + wj*16 + llo];

  for (int i = tid; i < BT*T_STEPS; i += 512)
    ys[i] = y[(size_t)b0*T_STEPS + i];

  // ---- hoisted staging pointers ----
  // A: slice-contiguous in hbf; advances +4096 ushorts (8KB) per slice;
  //    one -16*4096 correction at s==160 (t jumps to 9, kc back to 0).
  const ushort_t* asrc = hbf + (size_t)tile*T_STEPS*16*4096 + w*512 + lane*8;
  // W bases (wave-constant); per-slice offset = kc*512 ushorts.
  int c0 = w;                   // slot 0..7   : g=c0>>2, jt=c0&3
  int c1 = w + 8;               // slot 8..11  : waves 0..3 only
  const ushort_t* wsrc0 = wpack + ((size_t)((jb*4 + (c0&3))*4 + (c0>>2))*16)*512 + lane*8;
  const ushort_t* wsrc1 = wpack + ((size_t)((jb*4 + (c1&3))*4 + (c1>>2))*16)*512 + lane*8;
  const ushort_t* wsrcO = wpack + ((size_t)((jb*4 + (w&3))*4 + 3)*16)*512 + lane*8;

  auto stage = [&](int ns){
    int kc = ns & 15;
    if constexpr (PREP){
      gld_lds16(asrc, &Ab[ns&1][w*512]);
    } else {
      int row = tid & 127, kq = tid >> 7;
      int t = (ns < 160) ? (ns >> 4) : 9;
      const float* p = h + ((size_t)(b0+row)*T_STEPS + t)*512 + kc*32 + kq*8;
      float4 x0 = *(const float4*)p, x1 = *(const float4*)(p+4);
      uint4 pk;
      pk.x = pk2(x0.x,x0.y); pk.y = pk2(x0.z,x0.w);
      pk.z = pk2(x1.x,x1.y); pk.w = pk2(x1.z,x1.w);
      *(uint4*)&Ab[ns&1][tid*8] = pk;
    }
    if (ns < 160){
      gld_lds16(wsrc0 + (kc << 9), &Wb[ns&1][w*512]);
      if (w < 4)
        gld_lds16(wsrc1 + (kc << 9), &Wb[ns&1][(w+8)*512]);
    } else {
      if (w >= 4)
        gld_lds16(wsrcO + (kc << 9), &Wb[ns&1][(w-4)*512]);
    }
    asrc += 4096;
  };

  stage(0);
  __syncthreads();

  f32x4 acc[4][3];
  f32x4 acco[4];
  float cst[4][4];
#pragma unroll
  for (int m = 0; m < 4; ++m){
#pragma unroll
    for (int g = 0; g < 3; ++g) acc[m][g] = (f32x4){0.f,0.f,0.f,0.f};
    acco[m] = (f32x4){0.f,0.f,0.f,0.f};
#pragma unroll
    for (int r = 0; r < 4; ++r) cst[m][r] = 0.f;
  }

  // hoisted LDS read bases
  const ushort_t* abase[2] = { &Ab[0][(lhi*128 + mh*64 + llo)*8],
                               &Ab[1][(lhi*128 + mh*64 + llo)*8] };
  const ushort_t* wbase[2] = { &Wb[0][wj*512 + lane*8],
                               &Wb[1][wj*512 + lane*8] };

#pragma unroll 1
  for (int s = 0; s < 176; ++s){
    int ns = s + 1;
    if (ns < 176){
      if (ns == 160) asrc -= 16*4096;
      stage(ns);
    }

    const ushort_t* ap = abase[s&1];
    const ushort_t* wp = wbase[s&1];
    short8 af[4];
#pragma unroll
    for (int m = 0; m < 4; ++m)
      af[m] = *(const short8*)(ap + m*128);          // +16 rows = 128 ushorts

    if (s < 160){
#pragma unroll
      for (int g = 0; g < 3; ++g){
        short8 wf = *(const short8*)(wp + g*2048);   // +4 slots = 2048 ushorts
#pragma unroll
        for (int m = 0; m < 4; ++m)
          acc[m][g] = __builtin_amdgcn_mfma_f32_16x16x32_bf16(
              af[m], wf, acc[m][g], 0, 0, 0);
      }
      if ((s & 15) == 15){                           // end of K: cell update
        int t = s >> 4;
#pragma unroll
        for (int m = 0; m < 4; ++m)
#pragma unroll
          for (int r = 0; r < 4; ++r){
            float yr = ys[(mh*64 + m*16 + lhi*4 + r)*T_STEPS + t];
            float pi = acc[m][0][r] + fmaf(yr, wihv[0], bias2[0]);
            float pf = acc[m][1][r] + fmaf(yr, wihv[1], bias2[1]);
            float pg = acc[m][2][r] + fmaf(yr, wihv[2], bias2[2]);
            cst[m][r] = sigf(pf)*cst[m][r] + sigf(pi)*tanh_(pg);
          }
#pragma unroll
        for (int m = 0; m < 4; ++m)
#pragma unroll
          for (int g = 0; g < 3; ++g) acc[m][g] = (f32x4){0.f,0.f,0.f,0.f};
      }
    } else {                                         // o-gate sweep at t=9
      short8 wo = *(const short8*)wp;
#pragma unroll
      for (int m = 0; m < 4; ++m)
        acco[m] = __builtin_amdgcn_mfma_f32_16x16x32_bf16(
            af[m], wo, acco[m], 0, 0, 0);
    }
    __syncthreads();
  }

  // ---- epilogue: part = sig(o)*tanh(c)*v1, reduce over 16 j-lanes ----------
#pragma unroll
  for (int m = 0; m < 4; ++m)
#pragma unroll
    for (int r = 0; r < 4; ++r){
      float yr = ys[(mh*64 + m*16 + lhi*4 + r)*T_STEPS + 9];
      float po = acco[m][r] + fmaf(yr, wihv[3], bias2[3]);
      float val = sigf(po)*tanh_(cst[m][r])*v1v;
      val += __shfl_xor(val, 1);
      val += __shfl_xor(val, 2);
      val += __shfl_xor(val, 4);
      val += __shfl_xor(val, 8);
      if (llo == 0)
        atomicAdd(&out[b0 + mh*64 + m*16 + lhi*4 + r], val);
    }
}

extern "C" void kernel_launch(void* const* d_in, const int* in_sizes, int n_in,
                              void* d_out, int out_size, void* d_ws, size_t ws_size,
                              hipStream_t stream){
  (void)in_sizes; (void)n_in; (void)out_size;
  const float* h    = (const float*)d_in[0];
  const float* y    = (const float*)d_in[1];
  // d_in[2..7] = attention weights: mathematically dead (softmax over size-1 dim == 1)
  const float* Wih  = (const float*)d_in[8];
  const float* Whh  = (const float*)d_in[9];
  const float* bih  = (const float*)d_in[10];
  const float* bhh  = (const float*)d_in[11];
  const float* fc1w = (const float*)d_in[12];
  const float* fc1b = (const float*)d_in[13];
  const float* fc2w = (const float*)d_in[14];
  const float* fc2b = (const float*)d_in[15];
  float* out = (float*)d_out;

  ushort_t* wpack = (ushort_t*)d_ws;
  float* vbuf  = (float*)((char*)d_ws + VBUF_OFF);
  float* bias0 = vbuf + 1024;
  ushort_t* hbf = (ushort_t*)((char*)d_ws + HBF_OFF);
  bool prep = ws_size >= (size_t)HBF_OFF + HBF_BYTES;

  k_pack<<<512, 256, 0, stream>>>(Whh, wpack);
  k_v<<<17, 256, 0, stream>>>(fc1w, fc1b, fc2w, fc2b, vbuf, bias0);
  if (prep)
    k_prep<<<64*T_STEPS, 256, 0, stream>>>(h, hbf);
  k_init<<<128, 512, 0, stream>>>(h, vbuf, bias0, out);
  if (prep)
    k_main<true ><<<512, 512, 0, stream>>>(h, hbf, y, Wih, bih, bhh, wpack, vbuf, out);
  else
    k_main<false><<<512, 512, 0, stream>>>(h, hbf, y, Wih, bih, bhh, wpack, vbuf, out);
}

// Round 13
// 276.150 us; speedup vs baseline: 1.4411x; 1.4411x over previous
//
#include <hip/hip_runtime.h>
#include <stdint.h>

typedef __attribute__((ext_vector_type(8))) short short8;
typedef __attribute__((ext_vector_type(4))) float f32x4;
typedef unsigned short ushort_t;

#define T_STEPS 10
#define BT 128
#define WPACK_BYTES (2048*1024)                 // 2048 chunks x 1 KiB
#define VBUF_OFF  WPACK_BYTES
#define HBF_OFF   (WPACK_BYTES + 8192)
#define H_ELEMS   (8192ull*T_STEPS*512)
#define HBF_BYTES (H_ELEMS*2)

typedef const __attribute__((address_space(1))) void gas_void;
typedef __attribute__((address_space(3))) void las_void;

__device__ __forceinline__ void gld_lds16(const void* g, void* l){
  __builtin_amdgcn_global_load_lds((gas_void*)g, (las_void*)l, 16, 0, 0);
}

__device__ __forceinline__ unsigned int pk2(float x, float y){
  unsigned int bx = __float_as_uint(x), by = __float_as_uint(y);
  bx = (bx + 0x7FFFu + ((bx>>16)&1u)) >> 16;     // RNE fp32->bf16
  by = (by + 0x7FFFu + ((by>>16)&1u)) >> 16;
  return bx | (by<<16);
}
__device__ __forceinline__ float sigf(float x){ return 1.f/(1.f + __expf(-x)); }
__device__ __forceinline__ float tanh_(float x){
  x = fminf(fmaxf(x, -15.f), 15.f);
  float e = __expf(2.f*x);
  return (e - 1.f)/(e + 1.f);
}

// ---- K0a: pack W_hh [2048][512] fp32 -> bf16 B-fragment chunks -------------
// chunk = ((jb*4 + jt)*4 + g)*16 + kc  (jb 0..7 j-block of 64, jt 0..3)
// in-chunk lane = khi*16 + jl ; j = jb*64 + jt*16 + jl ; k = kc*32 + khi*8 ..
__global__ __launch_bounds__(256) void k_pack(const float* __restrict__ Whh,
                                              ushort_t* __restrict__ wp){
  int id  = blockIdx.x*256 + threadIdx.x;
  int row = id >> 6;
  int ko  = (id & 63) * 8;
  const float* p = Whh + row*512 + ko;
  float4 a = *(const float4*)p, b = *(const float4*)(p+4);
  uint4 v;
  v.x = pk2(a.x,a.y); v.y = pk2(a.z,a.w);
  v.z = pk2(b.x,b.y); v.w = pk2(b.z,b.w);
  int g = row >> 9, j = row & 511;
  int jb = j >> 6, jt = (j >> 4) & 3, jl = j & 15;
  int kc = ko >> 5, khi = (ko >> 3) & 3, lane = khi*16 + jl;
  int chunk = ((jb*4 + jt)*4 + g)*16 + kc;
  *(uint4*)(wp + chunk*512 + lane*8) = v;
}

// ---- K0b -------------------------------------------------------------------
__global__ __launch_bounds__(256) void k_v(const float* __restrict__ fc1w,
                                           const float* __restrict__ fc1b,
                                           const float* __restrict__ fc2w,
                                           const float* __restrict__ fc2b,
                                           float* __restrict__ vout,
                                           float* __restrict__ bias0){
  __shared__ float red[4][64];
  int tid = threadIdx.x;
  if (blockIdx.x < 16){
    int j  = blockIdx.x*64 + (tid & 63);
    int hc = tid >> 6;
    float s = 0.f;
    for (int hh = hc*128; hh < hc*128 + 128; ++hh)
      s += fc2w[hh] * fc1w[hh*1024 + j];
    red[hc][tid & 63] = s;
    __syncthreads();
    if (tid < 64)
      vout[blockIdx.x*64 + tid] = red[0][tid]+red[1][tid]+red[2][tid]+red[3][tid];
  } else {
    if (tid < 64){
      float s = 0.f;
      for (int i = 0; i < 8; ++i){ int hh = i*64 + tid; s += fc2w[hh]*fc1b[hh]; }
      for (int m = 32; m; m >>= 1) s += __shfl_xor(s, m);
      if (tid == 0) *bias0 = s + fc2b[0];
    }
  }
}

// ---- K2 --------------------------------------------------------------------
__global__ __launch_bounds__(512) void k_init(const float* __restrict__ h,
                                              const float* __restrict__ v,
                                              const float* __restrict__ bias0,
                                              float* __restrict__ out){
  int w = threadIdx.x >> 6, lane = threadIdx.x & 63;
  float b0v = *bias0;
  const float* v2 = v + 512;
  for (int r = 0; r < 8; ++r){
    int b = blockIdx.x*64 + w*8 + r;
    const float* hp = h + ((size_t)b*T_STEPS + 9)*512 + lane*8;
    float4 x0 = *(const float4*)hp, x1 = *(const float4*)(hp+4);
    const float* vp = v2 + lane*8;
    float4 w0 = *(const float4*)vp, w1 = *(const float4*)(vp+4);
    float s = x0.x*w0.x + x0.y*w0.y + x0.z*w0.z + x0.w*w0.w
            + x1.x*w1.x + x1.y*w1.y + x1.z*w1.z + x1.w*w1.w;
    for (int m = 32; m; m >>= 1) s += __shfl_xor(s, m);
    if (lane == 0) out[b] = s + b0v;
  }
}

// ---- K0c: h fp32 -> bf16 in quad-major per-slice layout --------------------
// hbf granule(16B) index = ((tile*10 + t)*16 + kc)*512 + kq*128 + row
__global__ __launch_bounds__(256) void k_prep(const float* __restrict__ h,
                                              ushort_t* __restrict__ hbf){
  __shared__ __align__(16) ushort_t buf[16*512*8];   // 128 KiB
  int T = blockIdx.x / T_STEPS, t = blockIdx.x % T_STEPS;
  int tid = threadIdx.x;
  int row = tid >> 1, half = tid & 1;
  const float* src = h + ((size_t)(T*128 + row)*T_STEPS + t)*512 + half*256;
#pragma unroll
  for (int g = 0; g < 32; ++g){
    int k0 = half*256 + g*8;
    float4 a = *(const float4*)(src + g*8);
    float4 b = *(const float4*)(src + g*8 + 4);
    uint4 pk;
    pk.x = pk2(a.x,a.y); pk.y = pk2(a.z,a.w);
    pk.z = pk2(b.x,b.y); pk.w = pk2(b.z,b.w);
    int kc = k0 >> 5, kq = (k0 >> 3) & 3;
    *(uint4*)&buf[(size_t)(kc*512 + kq*128 + row)*8] = pk;
  }
  __syncthreads();
  ushort_t* dst = hbf + ((size_t)(T*T_STEPS + t)*16)*4096;
#pragma unroll
  for (int i = 0; i < 32; ++i){
    int gr = tid + i*256;
    *(uint4*)(dst + gr*8) = *(const uint4*)&buf[gr*8];
  }
}

// ============================================================================
// K1: 256 threads (4 waves), 512 blocks (2/CU), waves_per_eu(2,2) -> 256 VGPR.
// Wave tile: m4 (64 rows) x n2 (32 j) x 3 gates = 24 MFMA/slice, acc 96 VGPR.
// A: LDS double-buffer via gld_lds (2 x 1KB/wave/slice).
// W: register-direct from L2 (6 x 1KB coalesced loads/wave/slice) - no LDS.
// Split loops overlay acc (main) and acco (o-sweep).
// ============================================================================
template<bool PREP>
__global__ __launch_bounds__(256)
__attribute__((amdgpu_waves_per_eu(2, 2)))
void k_main(
    const float* __restrict__ h, const ushort_t* __restrict__ hbf,
    const float* __restrict__ y,
    const float* __restrict__ Wih, const float* __restrict__ bih,
    const float* __restrict__ bhh,
    const ushort_t* __restrict__ wpack, const float* __restrict__ v1,
    float* __restrict__ out)
{
  __shared__ __align__(16) ushort_t Ab[2][4096];   // 2 x 8 KiB
  __shared__ float ys[BT*T_STEPS];                 // 5 KiB

  int tid = threadIdx.x;
  int w = tid >> 6, lane = tid & 63, lhi = lane >> 4, llo = lane & 15;
  int mh = w & 1, wj = w >> 1;                     // wave grid: 2 mh x 2 wj
  int bid = blockIdx.x;
  int xcd = bid & 7, q = bid >> 3;
  int jb = q >> 3, tile = xcd*8 + (q & 7);         // tile's jb-siblings same XCD
  int b0 = tile * BT;

  float bias2[4][2], wihv[4][2], v1v[2];
#pragma unroll
  for (int g = 0; g < 4; ++g)
#pragma unroll
    for (int n = 0; n < 2; ++n){
      int col = g*512 + jb*64 + (wj*2+n)*16 + llo;
      bias2[g][n] = bih[col] + bhh[col];
      wihv[g][n]  = Wih[col];
    }
#pragma unroll
  for (int n = 0; n < 2; ++n) v1v[n] = v1[jb*64 + (wj*2+n)*16 + llo];

  for (int i = tid; i < BT*T_STEPS; i += 256)
    ys[i] = y[(size_t)b0*T_STEPS + i];

  // A running source pointer (slice-contiguous hbf); wave covers 128 granules.
  const ushort_t* asrc = hbf + (size_t)tile*(T_STEPS*16)*4096 + (w*128 + lane)*8;
  // W per-lane base for this wave's jt-pair; frag (g,n) at +(n*4+g)*8192+kc*512.
  const ushort_t* wbase = wpack + (size_t)(jb*4 + wj*2)*4*8192 + lane*8;

  auto stageA = [&](int parity){
    if constexpr (PREP){
      gld_lds16(asrc,       &Ab[parity][w*1024]);
      gld_lds16(asrc + 512, &Ab[parity][w*1024 + 512]);
      asrc += 4096;
    }
  };
  auto stageA_f = [&](int parity, int ss){
    int t = (ss < 160) ? (ss >> 4) : 9;
    int kc = ss & 15;
#pragma unroll
    for (int i = 0; i < 2; ++i){
      int gidx = tid + i*256;
      int kq = gidx >> 7, row = gidx & 127;
      const float* p = h + ((size_t)(b0+row)*T_STEPS + t)*512 + kc*32 + kq*8;
      float4 x0 = *(const float4*)p, x1 = *(const float4*)(p+4);
      uint4 pk;
      pk.x = pk2(x0.x,x0.y); pk.y = pk2(x0.z,x0.w);
      pk.z = pk2(x1.x,x1.y); pk.w = pk2(x1.z,x1.w);
      *(uint4*)&Ab[parity][gidx*8] = pk;
    }
  };

  if constexpr (PREP) stageA(0); else stageA_f(0, 0);
  __syncthreads();

  f32x4 acc[4][3][2];
  float cst[4][2][4];
#pragma unroll
  for (int m = 0; m < 4; ++m)
#pragma unroll
    for (int n = 0; n < 2; ++n){
#pragma unroll
      for (int g = 0; g < 3; ++g) acc[m][g][n] = (f32x4){0.f,0.f,0.f,0.f};
#pragma unroll
      for (int r = 0; r < 4; ++r) cst[m][n][r] = 0.f;
    }

  const int aro = (lhi*128 + mh*64 + llo)*8;       // af base offset in Ab

  // ---- main loop: gates i,f,g~ over 160 slices (t x kc) -------------------
#pragma unroll 1
  for (int s = 0; s < 160; ++s){
    if (s < 159){
      if constexpr (PREP) stageA((s+1)&1); else stageA_f((s+1)&1, s+1);
    } else {
      if constexpr (PREP) { asrc -= 16*4096; stageA(0); }
      else stageA_f(0, 160);
    }

    int kco = (s & 15) * 512;
    short8 wf[3][2];
#pragma unroll
    for (int g = 0; g < 3; ++g)
#pragma unroll
      for (int n = 0; n < 2; ++n)
        wf[g][n] = *(const short8*)(wbase + (size_t)(n*4+g)*8192 + kco);

    const ushort_t* ap = &Ab[s&1][aro];
    short8 af[4];
#pragma unroll
    for (int m = 0; m < 4; ++m)
      af[m] = *(const short8*)(ap + m*128);

#pragma unroll
    for (int g = 0; g < 3; ++g)
#pragma unroll
      for (int n = 0; n < 2; ++n)
#pragma unroll
        for (int m = 0; m < 4; ++m)
          acc[m][g][n] = __builtin_amdgcn_mfma_f32_16x16x32_bf16(
              af[m], wf[g][n], acc[m][g][n], 0, 0, 0);

    if ((s & 15) == 15){
      int t = s >> 4;
#pragma unroll
      for (int m = 0; m < 4; ++m)
#pragma unroll
        for (int r = 0; r < 4; ++r){
          float yr = ys[(mh*64 + m*16 + lhi*4 + r)*T_STEPS + t];
#pragma unroll
          for (int n = 0; n < 2; ++n){
            float pi = acc[m][0][n][r] + fmaf(yr, wihv[0][n], bias2[0][n]);
            float pf = acc[m][1][n][r] + fmaf(yr, wihv[1][n], bias2[1][n]);
            float pg = acc[m][2][n][r] + fmaf(yr, wihv[2][n], bias2[2][n]);
            cst[m][n][r] = sigf(pf)*cst[m][n][r] + sigf(pi)*tanh_(pg);
          }
        }
#pragma unroll
      for (int m = 0; m < 4; ++m)
#pragma unroll
        for (int g = 0; g < 3; ++g)
#pragma unroll
          for (int n = 0; n < 2; ++n) acc[m][g][n] = (f32x4){0.f,0.f,0.f,0.f};
    }
    __syncthreads();
  }

  // ---- o-gate sweep: 16 slices at t=9 (acc dead -> acco overlays) ---------
  f32x4 acco[4][2];
#pragma unroll
  for (int m = 0; m < 4; ++m)
#pragma unroll
    for (int n = 0; n < 2; ++n) acco[m][n] = (f32x4){0.f,0.f,0.f,0.f};

#pragma unroll 1
  for (int s2 = 0; s2 < 16; ++s2){
    if (s2 < 15){
      if constexpr (PREP) stageA((s2+1)&1); else stageA_f((s2+1)&1, 161+s2);
    }
    int kco = s2 * 512;
    short8 wo[2];
#pragma unroll
    for (int n = 0; n < 2; ++n)
      wo[n] = *(const short8*)(wbase + (size_t)(n*4+3)*8192 + kco);

    const ushort_t* ap = &Ab[s2&1][aro];
    short8 af[4];
#pragma unroll
    for (int m = 0; m < 4; ++m)
      af[m] = *(const short8*)(ap + m*128);
#pragma unroll
    for (int n = 0; n < 2; ++n)
#pragma unroll
      for (int m = 0; m < 4; ++m)
        acco[m][n] = __builtin_amdgcn_mfma_f32_16x16x32_bf16(
            af[m], wo[n], acco[m][n], 0, 0, 0);
    __syncthreads();
  }

  // ---- epilogue: part = sig(o)*tanh(c)*v1, reduce over 16 j-lanes ----------
#pragma unroll
  for (int m = 0; m < 4; ++m)
#pragma unroll
    for (int r = 0; r < 4; ++r){
      float yr = ys[(mh*64 + m*16 + lhi*4 + r)*T_STEPS + 9];
      float val = 0.f;
#pragma unroll
      for (int n = 0; n < 2; ++n){
        float po = acco[m][n][r] + fmaf(yr, wihv[3][n], bias2[3][n]);
        val += sigf(po)*tanh_(cst[m][n][r])*v1v[n];
      }
      val += __shfl_xor(val, 1);
      val += __shfl_xor(val, 2);
      val += __shfl_xor(val, 4);
      val += __shfl_xor(val, 8);
      if (llo == 0)
        atomicAdd(&out[b0 + mh*64 + m*16 + lhi*4 + r], val);
    }
}

extern "C" void kernel_launch(void* const* d_in, const int* in_sizes, int n_in,
                              void* d_out, int out_size, void* d_ws, size_t ws_size,
                              hipStream_t stream){
  (void)in_sizes; (void)n_in; (void)out_size;
  const float* h    = (const float*)d_in[0];
  const float* y    = (const float*)d_in[1];
  // d_in[2..7] = attention weights: mathematically dead (softmax over size-1 dim == 1)
  const float* Wih  = (const float*)d_in[8];
  const float* Whh  = (const float*)d_in[9];
  const float* bih  = (const float*)d_in[10];
  const float* bhh  = (const float*)d_in[11];
  const float* fc1w = (const float*)d_in[12];
  const float* fc1b = (const float*)d_in[13];
  const float* fc2w = (const float*)d_in[14];
  const float* fc2b = (const float*)d_in[15];
  float* out = (float*)d_out;

  ushort_t* wpack = (ushort_t*)d_ws;
  float* vbuf  = (float*)((char*)d_ws + VBUF_OFF);
  float* bias0 = vbuf + 1024;
  ushort_t* hbf = (ushort_t*)((char*)d_ws + HBF_OFF);
  bool prep = ws_size >= (size_t)HBF_OFF + HBF_BYTES;

  k_pack<<<512, 256, 0, stream>>>(Whh, wpack);
  k_v<<<17, 256, 0, stream>>>(fc1w, fc1b, fc2w, fc2b, vbuf, bias0);
  if (prep)
    k_prep<<<64*T_STEPS, 256, 0, stream>>>(h, hbf);
  k_init<<<128, 512, 0, stream>>>(h, vbuf, bias0, out);
  if (prep)
    k_main<true ><<<512, 256, 0, stream>>>(h, hbf, y, Wih, bih, bhh, wpack, vbuf, out);
  else
    k_main<false><<<512, 256, 0, stream>>>(h, hbf, y, Wih, bih, bhh, wpack, vbuf, out);
}

// Round 14
// 253.960 us; speedup vs baseline: 1.5670x; 1.0874x over previous
//
#include <hip/hip_runtime.h>
#include <stdint.h>

typedef __attribute__((ext_vector_type(8))) short short8;
typedef __attribute__((ext_vector_type(4))) float f32x4;
typedef unsigned short ushort_t;

#define T_STEPS 10
#define BT 128
#define WPACK_BYTES (2048*1024)                 // 2048 chunks x 1 KiB
#define VBUF_OFF  WPACK_BYTES
#define HBF_OFF   (WPACK_BYTES + 8192)
#define H_ELEMS   (8192ull*T_STEPS*512)
#define HBF_BYTES (H_ELEMS*2)

typedef const __attribute__((address_space(1))) void gas_void;
typedef __attribute__((address_space(3))) void las_void;

__device__ __forceinline__ void gld_lds16(const void* g, void* l){
  __builtin_amdgcn_global_load_lds((gas_void*)g, (las_void*)l, 16, 0, 0);
}

__device__ __forceinline__ unsigned int pk2(float x, float y){
  unsigned int bx = __float_as_uint(x), by = __float_as_uint(y);
  bx = (bx + 0x7FFFu + ((bx>>16)&1u)) >> 16;     // RNE fp32->bf16
  by = (by + 0x7FFFu + ((by>>16)&1u)) >> 16;
  return bx | (by<<16);
}
__device__ __forceinline__ float sigf(float x){ return 1.f/(1.f + __expf(-x)); }
__device__ __forceinline__ float tanh_(float x){
  x = fminf(fmaxf(x, -15.f), 15.f);
  float e = __expf(2.f*x);
  return (e - 1.f)/(e + 1.f);
}

// ---- K0a: pack W_hh [2048][512] fp32 -> bf16 B-fragment chunks -------------
// chunk = ((jb*4 + jt)*4 + g)*16 + kc  (jb 0..7 j-block of 64, jt 0..3)
__global__ __launch_bounds__(256) void k_pack(const float* __restrict__ Whh,
                                              ushort_t* __restrict__ wp){
  int id  = blockIdx.x*256 + threadIdx.x;
  int row = id >> 6;
  int ko  = (id & 63) * 8;
  const float* p = Whh + row*512 + ko;
  float4 a = *(const float4*)p, b = *(const float4*)(p+4);
  uint4 v;
  v.x = pk2(a.x,a.y); v.y = pk2(a.z,a.w);
  v.z = pk2(b.x,b.y); v.w = pk2(b.z,b.w);
  int g = row >> 9, j = row & 511;
  int jb = j >> 6, jt = (j >> 4) & 3, jl = j & 15;
  int kc = ko >> 5, khi = (ko >> 3) & 3, lane = khi*16 + jl;
  int chunk = ((jb*4 + jt)*4 + g)*16 + kc;
  *(uint4*)(wp + chunk*512 + lane*8) = v;
}

// ---- K0b -------------------------------------------------------------------
__global__ __launch_bounds__(256) void k_v(const float* __restrict__ fc1w,
                                           const float* __restrict__ fc1b,
                                           const float* __restrict__ fc2w,
                                           const float* __restrict__ fc2b,
                                           float* __restrict__ vout,
                                           float* __restrict__ bias0){
  __shared__ float red[4][64];
  int tid = threadIdx.x;
  if (blockIdx.x < 16){
    int j  = blockIdx.x*64 + (tid & 63);
    int hc = tid >> 6;
    float s = 0.f;
    for (int hh = hc*128; hh < hc*128 + 128; ++hh)
      s += fc2w[hh] * fc1w[hh*1024 + j];
    red[hc][tid & 63] = s;
    __syncthreads();
    if (tid < 64)
      vout[blockIdx.x*64 + tid] = red[0][tid]+red[1][tid]+red[2][tid]+red[3][tid];
  } else {
    if (tid < 64){
      float s = 0.f;
      for (int i = 0; i < 8; ++i){ int hh = i*64 + tid; s += fc2w[hh]*fc1b[hh]; }
      for (int m = 32; m; m >>= 1) s += __shfl_xor(s, m);
      if (tid == 0) *bias0 = s + fc2b[0];
    }
  }
}

// ---- K2 --------------------------------------------------------------------
__global__ __launch_bounds__(512) void k_init(const float* __restrict__ h,
                                              const float* __restrict__ v,
                                              const float* __restrict__ bias0,
                                              float* __restrict__ out){
  int w = threadIdx.x >> 6, lane = threadIdx.x & 63;
  float b0v = *bias0;
  const float* v2 = v + 512;
  for (int r = 0; r < 8; ++r){
    int b = blockIdx.x*64 + w*8 + r;
    const float* hp = h + ((size_t)b*T_STEPS + 9)*512 + lane*8;
    float4 x0 = *(const float4*)hp, x1 = *(const float4*)(hp+4);
    const float* vp = v2 + lane*8;
    float4 w0 = *(const float4*)vp, w1 = *(const float4*)(vp+4);
    float s = x0.x*w0.x + x0.y*w0.y + x0.z*w0.z + x0.w*w0.w
            + x1.x*w1.x + x1.y*w1.y + x1.z*w1.z + x1.w*w1.w;
    for (int m = 32; m; m >>= 1) s += __shfl_xor(s, m);
    if (lane == 0) out[b] = s + b0v;
  }
}

// ---- K0c: h fp32 -> bf16 in quad-major per-slice layout --------------------
// hbf granule(16B) index = ((tile*10 + t)*16 + kc)*512 + kq*128 + row
__global__ __launch_bounds__(256) void k_prep(const float* __restrict__ h,
                                              ushort_t* __restrict__ hbf){
  __shared__ __align__(16) ushort_t buf[16*512*8];   // 128 KiB
  int T = blockIdx.x / T_STEPS, t = blockIdx.x % T_STEPS;
  int tid = threadIdx.x;
  int row = tid >> 1, half = tid & 1;
  const float* src = h + ((size_t)(T*128 + row)*T_STEPS + t)*512 + half*256;
#pragma unroll
  for (int g = 0; g < 32; ++g){
    int k0 = half*256 + g*8;
    float4 a = *(const float4*)(src + g*8);
    float4 b = *(const float4*)(src + g*8 + 4);
    uint4 pk;
    pk.x = pk2(a.x,a.y); pk.y = pk2(a.z,a.w);
    pk.z = pk2(b.x,b.y); pk.w = pk2(b.z,b.w);
    int kc = k0 >> 5, kq = (k0 >> 3) & 3;
    *(uint4*)&buf[(size_t)(kc*512 + kq*128 + row)*8] = pk;
  }
  __syncthreads();
  ushort_t* dst = hbf + ((size_t)(T*T_STEPS + t)*16)*4096;
#pragma unroll
  for (int i = 0; i < 32; ++i){
    int gr = tid + i*256;
    *(uint4*)(dst + gr*8) = *(const uint4*)&buf[gr*8];
  }
}

// ============================================================================
// K1 (PREP): fully register-direct. 256 threads (4 waves), 512 blocks (2/CU).
// NO LDS staging, NO main-loop barriers. A and W fragments loaded straight
// from L2 (hbf quad-major + wpack fragment-packed, both coalesced 16B/lane).
// Explicit 2-deep register double-buffer (named sets, static indexing).
// ============================================================================
__global__ __launch_bounds__(256)
__attribute__((amdgpu_waves_per_eu(2, 2)))
void k_main_r(const ushort_t* __restrict__ hbf, const float* __restrict__ y,
              const float* __restrict__ Wih, const float* __restrict__ bih,
              const float* __restrict__ bhh,
              const ushort_t* __restrict__ wpack, const float* __restrict__ v1,
              float* __restrict__ out)
{
  __shared__ float ys[BT*T_STEPS];                 // 5 KiB (only LDS use)

  int tid = threadIdx.x;
  int w = tid >> 6, lane = tid & 63, lhi = lane >> 4, llo = lane & 15;
  int mh = w & 1, wj = w >> 1;                     // wave grid: 2 mh x 2 wj
  int bid = blockIdx.x;
  int xcd = bid & 7, q = bid >> 3;
  int jb = q >> 3, tile = xcd*8 + (q & 7);         // jb-siblings same XCD
  int b0 = tile * BT;

  float bias2[4][2], wihv[4][2], v1v[2];
#pragma unroll
  for (int g = 0; g < 4; ++g)
#pragma unroll
    for (int n = 0; n < 2; ++n){
      int col = g*512 + jb*64 + (wj*2+n)*16 + llo;
      bias2[g][n] = bih[col] + bhh[col];
      wihv[g][n]  = Wih[col];
    }
#pragma unroll
  for (int n = 0; n < 2; ++n) v1v[n] = v1[jb*64 + (wj*2+n)*16 + llo];

  for (int i = tid; i < BT*T_STEPS; i += 256)
    ys[i] = y[(size_t)b0*T_STEPS + i];
  __syncthreads();

  // A fragment base: granule (lhi*128 + mh*64 + m*16 + llo) within slice;
  // slice stride 4096 ushorts, t stride 65536, tile stride 655360.
  const ushort_t* abase = hbf + (size_t)tile*655360
                        + (size_t)(lhi*128 + mh*64 + llo)*8;
  // W fragment (g,n,kc) at wbase + (n*4+g)*8192 + kc*512.
  const ushort_t* wbase = wpack + (size_t)(jb*4 + wj*2)*32768 + lane*8;

  f32x4 acc[4][3][2];
  float cst[4][2][4];
#pragma unroll
  for (int m = 0; m < 4; ++m)
#pragma unroll
    for (int n = 0; n < 2; ++n){
#pragma unroll
      for (int g = 0; g < 3; ++g) acc[m][g][n] = (f32x4){0.f,0.f,0.f,0.f};
#pragma unroll
      for (int r = 0; r < 4; ++r) cst[m][n][r] = 0.f;
    }

  const ushort_t* aT = abase;
#pragma unroll 1
  for (int t = 0; t < T_STEPS; ++t){
    short8 afA[4], wfA[3][2], afB[4], wfB[3][2];
    const ushort_t* ap = aT;                 // kc=0 position
    const ushort_t* wk = wbase;              // kc=0 position

    // prologue: set A <- kc 0
#pragma unroll
    for (int m = 0; m < 4; ++m) afA[m] = *(const short8*)(ap + m*128);
#pragma unroll
    for (int g = 0; g < 3; ++g)
#pragma unroll
      for (int n = 0; n < 2; ++n)
        wfA[g][n] = *(const short8*)(wk + (size_t)(n*4+g)*8192);

#pragma unroll 1
    for (int kp = 0; kp < 8; ++kp){
      // load set B <- kc 2kp+1
#pragma unroll
      for (int m = 0; m < 4; ++m) afB[m] = *(const short8*)(ap + 4096 + m*128);
#pragma unroll
      for (int g = 0; g < 3; ++g)
#pragma unroll
        for (int n = 0; n < 2; ++n)
          wfB[g][n] = *(const short8*)(wk + (size_t)(n*4+g)*8192 + 512);
      // MFMA set A
#pragma unroll
      for (int g = 0; g < 3; ++g)
#pragma unroll
        for (int n = 0; n < 2; ++n)
#pragma unroll
          for (int m = 0; m < 4; ++m)
            acc[m][g][n] = __builtin_amdgcn_mfma_f32_16x16x32_bf16(
                afA[m], wfA[g][n], acc[m][g][n], 0, 0, 0);
      // load set A <- kc 2kp+2 (guard: stay within kc<=15)
      if (kp < 7){
#pragma unroll
        for (int m = 0; m < 4; ++m) afA[m] = *(const short8*)(ap + 8192 + m*128);
#pragma unroll
        for (int g = 0; g < 3; ++g)
#pragma unroll
          for (int n = 0; n < 2; ++n)
            wfA[g][n] = *(const short8*)(wk + (size_t)(n*4+g)*8192 + 1024);
      }
      // MFMA set B
#pragma unroll
      for (int g = 0; g < 3; ++g)
#pragma unroll
        for (int n = 0; n < 2; ++n)
#pragma unroll
          for (int m = 0; m < 4; ++m)
            acc[m][g][n] = __builtin_amdgcn_mfma_f32_16x16x32_bf16(
                afB[m], wfB[g][n], acc[m][g][n], 0, 0, 0);
      ap += 8192;
      wk += 1024;
    }

    // cell update
#pragma unroll
    for (int m = 0; m < 4; ++m)
#pragma unroll
      for (int r = 0; r < 4; ++r){
        float yr = ys[(mh*64 + m*16 + lhi*4 + r)*T_STEPS + t];
#pragma unroll
        for (int n = 0; n < 2; ++n){
          float pi = acc[m][0][n][r] + fmaf(yr, wihv[0][n], bias2[0][n]);
          float pf = acc[m][1][n][r] + fmaf(yr, wihv[1][n], bias2[1][n]);
          float pg = acc[m][2][n][r] + fmaf(yr, wihv[2][n], bias2[2][n]);
          cst[m][n][r] = sigf(pf)*cst[m][n][r] + sigf(pi)*tanh_(pg);
        }
      }
#pragma unroll
    for (int m = 0; m < 4; ++m)
#pragma unroll
      for (int g = 0; g < 3; ++g)
#pragma unroll
        for (int n = 0; n < 2; ++n) acc[m][g][n] = (f32x4){0.f,0.f,0.f,0.f};

    aT += 65536;
  }

  // ---- o-gate sweep at t=9 (register-direct, dbuf'd the same way) ---------
  f32x4 acco[4][2];
#pragma unroll
  for (int m = 0; m < 4; ++m)
#pragma unroll
    for (int n = 0; n < 2; ++n) acco[m][n] = (f32x4){0.f,0.f,0.f,0.f};

  {
    const ushort_t* ap = abase + (size_t)9*65536;
    const ushort_t* wk = wbase + (size_t)3*8192;   // g=3 plane
    short8 afA[4], woA[2], afB[4], woB[2];
#pragma unroll
    for (int m = 0; m < 4; ++m) afA[m] = *(const short8*)(ap + m*128);
#pragma unroll
    for (int n = 0; n < 2; ++n) woA[n] = *(const short8*)(wk + (size_t)n*32768);

#pragma unroll 1
    for (int kp = 0; kp < 8; ++kp){
#pragma unroll
      for (int m = 0; m < 4; ++m) afB[m] = *(const short8*)(ap + 4096 + m*128);
#pragma unroll
      for (int n = 0; n < 2; ++n)
        woB[n] = *(const short8*)(wk + (size_t)n*32768 + 512);
#pragma unroll
      for (int n = 0; n < 2; ++n)
#pragma unroll
        for (int m = 0; m < 4; ++m)
          acco[m][n] = __builtin_amdgcn_mfma_f32_16x16x32_bf16(
              afA[m], woA[n], acco[m][n], 0, 0, 0);
      if (kp < 7){
#pragma unroll
        for (int m = 0; m < 4; ++m) afA[m] = *(const short8*)(ap + 8192 + m*128);
#pragma unroll
        for (int n = 0; n < 2; ++n)
          woA[n] = *(const short8*)(wk + (size_t)n*32768 + 1024);
      }
#pragma unroll
      for (int n = 0; n < 2; ++n)
#pragma unroll
        for (int m = 0; m < 4; ++m)
          acco[m][n] = __builtin_amdgcn_mfma_f32_16x16x32_bf16(
              afB[m], woB[n], acco[m][n], 0, 0, 0);
      ap += 8192;
      wk += 1024;
    }
  }

  // ---- epilogue: part = sig(o)*tanh(c)*v1, reduce over 16 j-lanes ----------
#pragma unroll
  for (int m = 0; m < 4; ++m)
#pragma unroll
    for (int r = 0; r < 4; ++r){
      float yr = ys[(mh*64 + m*16 + lhi*4 + r)*T_STEPS + 9];
      float val = 0.f;
#pragma unroll
      for (int n = 0; n < 2; ++n){
        float po = acco[m][n][r] + fmaf(yr, wihv[3][n], bias2[3][n]);
        val += sigf(po)*tanh_(cst[m][n][r])*v1v[n];
      }
      val += __shfl_xor(val, 1);
      val += __shfl_xor(val, 2);
      val += __shfl_xor(val, 4);
      val += __shfl_xor(val, 8);
      if (llo == 0)
        atomicAdd(&out[b0 + mh*64 + m*16 + lhi*4 + r], val);
    }
}

// ============================================================================
// K1 fallback (!PREP): R13 structure — A staged to LDS from fp32 h, W direct.
// ============================================================================
__global__ __launch_bounds__(256)
__attribute__((amdgpu_waves_per_eu(2, 2)))
void k_main_f(const float* __restrict__ h, const float* __restrict__ y,
              const float* __restrict__ Wih, const float* __restrict__ bih,
              const float* __restrict__ bhh,
              const ushort_t* __restrict__ wpack, const float* __restrict__ v1,
              float* __restrict__ out)
{
  __shared__ __align__(16) ushort_t Ab[2][4096];
  __shared__ float ys[BT*T_STEPS];

  int tid = threadIdx.x;
  int w = tid >> 6, lane = tid & 63, lhi = lane >> 4, llo = lane & 15;
  int mh = w & 1, wj = w >> 1;
  int bid = blockIdx.x;
  int xcd = bid & 7, q = bid >> 3;
  int jb = q >> 3, tile = xcd*8 + (q & 7);
  int b0 = tile * BT;

  float bias2[4][2], wihv[4][2], v1v[2];
#pragma unroll
  for (int g = 0; g < 4; ++g)
#pragma unroll
    for (int n = 0; n < 2; ++n){
      int col = g*512 + jb*64 + (wj*2+n)*16 + llo;
      bias2[g][n] = bih[col] + bhh[col];
      wihv[g][n]  = Wih[col];
    }
#pragma unroll
  for (int n = 0; n < 2; ++n) v1v[n] = v1[jb*64 + (wj*2+n)*16 + llo];

  for (int i = tid; i < BT*T_STEPS; i += 256)
    ys[i] = y[(size_t)b0*T_STEPS + i];

  const ushort_t* wbase = wpack + (size_t)(jb*4 + wj*2)*32768 + lane*8;

  auto stageA_f = [&](int parity, int ss){
    int t = (ss < 160) ? (ss >> 4) : 9;
    int kc = ss & 15;
#pragma unroll
    for (int i = 0; i < 2; ++i){
      int gidx = tid + i*256;
      int kq = gidx >> 7, row = gidx & 127;
      const float* p = h + ((size_t)(b0+row)*T_STEPS + t)*512 + kc*32 + kq*8;
      float4 x0 = *(const float4*)p, x1 = *(const float4*)(p+4);
      uint4 pk;
      pk.x = pk2(x0.x,x0.y); pk.y = pk2(x0.z,x0.w);
      pk.z = pk2(x1.x,x1.y); pk.w = pk2(x1.z,x1.w);
      *(uint4*)&Ab[parity][gidx*8] = pk;
    }
  };

  stageA_f(0, 0);
  __syncthreads();

  f32x4 acc[4][3][2];
  float cst[4][2][4];
#pragma unroll
  for (int m = 0; m < 4; ++m)
#pragma unroll
    for (int n = 0; n < 2; ++n){
#pragma unroll
      for (int g = 0; g < 3; ++g) acc[m][g][n] = (f32x4){0.f,0.f,0.f,0.f};
#pragma unroll
      for (int r = 0; r < 4; ++r) cst[m][n][r] = 0.f;
    }

  const int aro = (lhi*128 + mh*64 + llo)*8;

#pragma unroll 1
  for (int s = 0; s < 160; ++s){
    if (s < 159) stageA_f((s+1)&1, s+1);
    else         stageA_f(0, 160);

    int kco = (s & 15) * 512;
    short8 wf[3][2];
#pragma unroll
    for (int g = 0; g < 3; ++g)
#pragma unroll
      for (int n = 0; n < 2; ++n)
        wf[g][n] = *(const short8*)(wbase + (size_t)(n*4+g)*8192 + kco);

    const ushort_t* ap = &Ab[s&1][aro];
    short8 af[4];
#pragma unroll
    for (int m = 0; m < 4; ++m)
      af[m] = *(const short8*)(ap + m*128);

#pragma unroll
    for (int g = 0; g < 3; ++g)
#pragma unroll
      for (int n = 0; n < 2; ++n)
#pragma unroll
        for (int m = 0; m < 4; ++m)
          acc[m][g][n] = __builtin_amdgcn_mfma_f32_16x16x32_bf16(
              af[m], wf[g][n], acc[m][g][n], 0, 0, 0);

    if ((s & 15) == 15){
      int t = s >> 4;
#pragma unroll
      for (int m = 0; m < 4; ++m)
#pragma unroll
        for (int r = 0; r < 4; ++r){
          float yr = ys[(mh*64 + m*16 + lhi*4 + r)*T_STEPS + t];
#pragma unroll
          for (int n = 0; n < 2; ++n){
            float pi = acc[m][0][n][r] + fmaf(yr, wihv[0][n], bias2[0][n]);
            float pf = acc[m][1][n][r] + fmaf(yr, wihv[1][n], bias2[1][n]);
            float pg = acc[m][2][n][r] + fmaf(yr, wihv[2][n], bias2[2][n]);
            cst[m][n][r] = sigf(pf)*cst[m][n][r] + sigf(pi)*tanh_(pg);
          }
        }
#pragma unroll
      for (int m = 0; m < 4; ++m)
#pragma unroll
        for (int g = 0; g < 3; ++g)
#pragma unroll
          for (int n = 0; n < 2; ++n) acc[m][g][n] = (f32x4){0.f,0.f,0.f,0.f};
    }
    __syncthreads();
  }

  f32x4 acco[4][2];
#pragma unroll
  for (int m = 0; m < 4; ++m)
#pragma unroll
    for (int n = 0; n < 2; ++n) acco[m][n] = (f32x4){0.f,0.f,0.f,0.f};

#pragma unroll 1
  for (int s2 = 0; s2 < 16; ++s2){
    if (s2 < 15) stageA_f((s2+1)&1, 161+s2);
    int kco = s2 * 512;
    short8 wo[2];
#pragma unroll
    for (int n = 0; n < 2; ++n)
      wo[n] = *(const short8*)(wbase + (size_t)(n*4+3)*8192 + kco);

    const ushort_t* ap = &Ab[s2&1][aro];
    short8 af[4];
#pragma unroll
    for (int m = 0; m < 4; ++m)
      af[m] = *(const short8*)(ap + m*128);
#pragma unroll
    for (int n = 0; n < 2; ++n)
#pragma unroll
      for (int m = 0; m < 4; ++m)
        acco[m][n] = __builtin_amdgcn_mfma_f32_16x16x32_bf16(
            af[m], wo[n], acco[m][n], 0, 0, 0);
    __syncthreads();
  }

#pragma unroll
  for (int m = 0; m < 4; ++m)
#pragma unroll
    for (int r = 0; r < 4; ++r){
      float yr = ys[(mh*64 + m*16 + lhi*4 + r)*T_STEPS + 9];
      float val = 0.f;
#pragma unroll
      for (int n = 0; n < 2; ++n){
        float po = acco[m][n][r] + fmaf(yr, wihv[3][n], bias2[3][n]);
        val += sigf(po)*tanh_(cst[m][n][r])*v1v[n];
      }
      val += __shfl_xor(val, 1);
      val += __shfl_xor(val, 2);
      val += __shfl_xor(val, 4);
      val += __shfl_xor(val, 8);
      if (llo == 0)
        atomicAdd(&out[b0 + mh*64 + m*16 + lhi*4 + r], val);
    }
}

extern "C" void kernel_launch(void* const* d_in, const int* in_sizes, int n_in,
                              void* d_out, int out_size, void* d_ws, size_t ws_size,
                              hipStream_t stream){
  (void)in_sizes; (void)n_in; (void)out_size;
  const float* h    = (const float*)d_in[0];
  const float* y    = (const float*)d_in[1];
  // d_in[2..7] = attention weights: mathematically dead (softmax over size-1 dim == 1)
  const float* Wih  = (const float*)d_in[8];
  const float* Whh  = (const float*)d_in[9];
  const float* bih  = (const float*)d_in[10];
  const float* bhh  = (const float*)d_in[11];
  const float* fc1w = (const float*)d_in[12];
  const float* fc1b = (const float*)d_in[13];
  const float* fc2w = (const float*)d_in[14];
  const float* fc2b = (const float*)d_in[15];
  float* out = (float*)d_out;

  ushort_t* wpack = (ushort_t*)d_ws;
  float* vbuf  = (float*)((char*)d_ws + VBUF_OFF);
  float* bias0 = vbuf + 1024;
  ushort_t* hbf = (ushort_t*)((char*)d_ws + HBF_OFF);
  bool prep = ws_size >= (size_t)HBF_OFF + HBF_BYTES;

  k_pack<<<512, 256, 0, stream>>>(Whh, wpack);
  k_v<<<17, 256, 0, stream>>>(fc1w, fc1b, fc2w, fc2b, vbuf, bias0);
  if (prep)
    k_prep<<<64*T_STEPS, 256, 0, stream>>>(h, hbf);
  k_init<<<128, 512, 0, stream>>>(h, vbuf, bias0, out);
  if (prep)
    k_main_r<<<512, 256, 0, stream>>>(hbf, y, Wih, bih, bhh, wpack, vbuf, out);
  else
    k_main_f<<<512, 256, 0, stream>>>(h, y, Wih, bih, bhh, wpack, vbuf, out);
}